// Round 9
// baseline (177.327 us; speedup 1.0000x reference)
//
#include <hip/hip_runtime.h>

// crossCorrelation3D: local (9x9x9) normalized cross-correlation loss, fused.
// B=2, C=1, D=H=W=160, fp32. Output = -mean(cc), scalar.
//
// R9: controlled-drain pipeline. R8 post-mortem: per-iter 1230 cyc vs ~720
// LDS work; gap = 3 __syncthreads each emitting s_waitcnt vmcnt(0) (the m97
// barrier-drain problem) — the same-region DMA latency exposed every iter.
// Also: SQ_LDS_BANK_CONFLICT ~1e7 is a b128 delivery artifact (8-phase/op,
// all patterns verified even) — not a lever.
//  1. ALL VMEM = global_load_lds with LDS consumers (flow too: 16x16 tile
//     DMA'd to flT, read back as ds_read) -> compiler inserts no VMEM waits
//     in the loop; draining is entirely ours.
//  2. TWO raw barriers/iter: X = vmcnt(0)+lgkmcnt(0) at iter START (only
//     vm-drain; waits on DMAs issued a full phase+barrier+phase earlier,
//     ~550cyc cover); W = lgkmcnt(0) only (in-flight DMA rides through).
//  3. iter l: X | P1: issue dma(l+1)->inT[(l+1)&1], flow(l)->flT[l&1],
//     step2(l) | W | P2: hpass(l)->Pb[l&1], ring(plane l-1 from
//     Pb[(l-1)&1]), cc(j=l-9, flv=flT[(l-1)&1]).
//  Hazards (pairwise): tmp5 w P1(l) / r P2(l): W. r P2(l) / w P1(l+1): X.
//    Pb[l&1] w P2(l) / r P2(l+1): X,W. r / next w P2(l+2): X,W.
//    inT[(l+1)&1]: issue P1(l) (after X(l), so prior readers done), lands
//    <= X(l+1), read P1(l+1). flT same pattern one parity off.
//  Clamped-address DMA always issues; garbage planes filtered by vz at ring
//  (R8-verified pattern). Borders: exec-masked lanes never write; init
//  inT=0, tgT=-1 (transform t=(raw+1)/2 in step2 -> border t=0 = zero-pad).

constexpr int NB = 2;
constexpr int ND = 160;
constexpr int NH = 160;
constexpr int NW = 160;
constexpr int TH = 16;
constexpr int TW = 16;
constexpr int DCHUNK = 32;
constexpr int NDCH = ND / DCHUNK;        // 5
constexpr int NPL = DCHUNK + 8;          // 40 planes
constexpr int NIT = NPL + 1;             // 41 iterations (l = 0..40)
constexpr int TRS = 20;                  // tmp5 row stride (floats)
constexpr int TFS = 24 * TRS + 8;        // 488 (mod 32 = 8: hpass reads even)
constexpr int PRS = 16;                  // Pb row stride
constexpr int PFS = 16 * PRS + 8;        // 264 (mod 32 = 8)
constexpr float INV_K = 1.0f / 729.0f;
constexpr double INV_COUNT = 1.0 / (double(NB) * ND * NH * NW); // 1/8192000

__device__ __forceinline__ void gld_lds16(const float* g, float* l)
{
    __builtin_amdgcn_global_load_lds(
        (const __attribute__((address_space(1))) void*)g,
        (__attribute__((address_space(3))) void*)l, 16, 0, 0);
}

// X barrier: the ONLY vm drain point. Waits DMAs issued >= one full
// phase+barrier+phase earlier (~550cyc cover).
__device__ __forceinline__ void bar_vm0()
{
    asm volatile("s_waitcnt vmcnt(0) lgkmcnt(0)" ::: "memory");
    __builtin_amdgcn_s_barrier();
    __builtin_amdgcn_sched_barrier(0);
}
// W barrier: LDS visibility only; in-flight global_load_lds rides through.
__device__ __forceinline__ void bar_ds()
{
    asm volatile("s_waitcnt lgkmcnt(0)" ::: "memory");
    __builtin_amdgcn_s_barrier();
    __builtin_amdgcn_sched_barrier(0);
}

// DMA one 24x24 halo plane (input & raw target) into inT/tgT.
// Slot = tid (float4), lane-linear: wave-uniform LDS base + lane*16B.
// OOB (h/w) lanes exec-masked -> border slots keep init (0 / -1) forever.
// dp must be pre-clamped to [0, ND).
__device__ __forceinline__ void dma_plane(const float* __restrict__ in,
                                          const float* __restrict__ tg,
                                          float* __restrict__ inT,
                                          float* __restrict__ tgT,
                                          int b, int dp, int h0, int w0, int tid)
{
    if (tid < 144) {
        int r = tid / 6;
        int q = tid - r * 6;
        int gh = h0 - 4 + r;
        int gw = w0 - 4 + q * 4;
        int wb = (tid >> 6) * 256;        // wave-uniform float offset
        if (((unsigned)gh < (unsigned)NH) && ((unsigned)gw < (unsigned)NW)) {
            int base = ((b * ND + dp) * NH + gh) * NW + gw;   // fits int32
            gld_lds16(in + base, inT + wb);
            gld_lds16(tg + base, tgT + wb);
        }
    }
}

// DMA the 16x16 flow tile for plane dout into flT (wave 0 only; lane i
// covers (hh = i>>2, ww = 4*(i&3))..+3 -> flT flat = tid mapping).
__device__ __forceinline__ void dma_flow(const float* __restrict__ fl,
                                         float* __restrict__ flT,
                                         int b, int dout, int h0, int w0, int tid)
{
    if (tid < 64) {
        int gh = h0 + (tid >> 2);
        int gw = w0 + ((tid & 3) << 2);
        int base = ((b * ND + dout) * NH + gh) * NW + gw;
        gld_lds16(fl + base, flT);
    }
}

// w-direction 9-sums, quad form. Thread (r,q): outputs wo=4q..4q+3 of row r
// need inputs 4q..4q+11 (3 b128 per array). Target transform applied HERE
// (tgT holds raw values; border slots = -1 -> t = 0 = zero padding).
#define W9SLIDE(EXPR, FI)                                                  \
    {                                                                      \
        float p0 = (EXPR(0)), p1 = (EXPR(1)), p2 = (EXPR(2)),              \
              p3 = (EXPR(3)), p4 = (EXPR(4)), p5 = (EXPR(5)),              \
              p6 = (EXPR(6)), p7 = (EXPR(7)), p8 = (EXPR(8)),              \
              p9 = (EXPR(9)), p10 = (EXPR(10)), p11 = (EXPR(11));          \
        float s = p0 + p1 + p2 + p3 + p4 + p5 + p6 + p7 + p8;              \
        float4 o;                                                          \
        o.x = s; s += p9 - p0;                                             \
        o.y = s; s += p10 - p1;                                            \
        o.z = s; s += p11 - p2;                                            \
        o.w = s;                                                           \
        *reinterpret_cast<float4*>(outp + (FI) * TFS) = o;                 \
    }

__device__ __forceinline__ void step2q(int tid, const float* __restrict__ inT,
                                       const float* __restrict__ tgT,
                                       float* __restrict__ t5)
{
    const int r = tid >> 2, q = tid & 3;
    const float4* ip = reinterpret_cast<const float4*>(inT + r * 24 + 4 * q);
    const float4* tp = reinterpret_cast<const float4*>(tgT + r * 24 + 4 * q);
    const float4 i0 = ip[0], i1 = ip[1], i2 = ip[2];
    const float4 t0 = tp[0], t1 = tp[1], t2 = tp[2];
    const float ia[12] = {i0.x, i0.y, i0.z, i0.w, i1.x, i1.y, i1.z, i1.w,
                          i2.x, i2.y, i2.z, i2.w};
    float ta[12] = {t0.x, t0.y, t0.z, t0.w, t1.x, t1.y, t1.z, t1.w,
                    t2.x, t2.y, t2.z, t2.w};
    #pragma unroll
    for (int j = 0; j < 12; ++j) ta[j] = fmaf(ta[j], 0.5f, 0.5f);
    float* outp = t5 + r * TRS + 4 * q;
    #define E_T(j)  ta[j]
    #define E_I(j)  ia[j]
    #define E_TT(j) (ta[j] * ta[j])
    #define E_II(j) (ia[j] * ia[j])
    #define E_IT(j) (ia[j] * ta[j])
    W9SLIDE(E_T, 0)
    W9SLIDE(E_I, 1)
    W9SLIDE(E_TT, 2)
    W9SLIDE(E_II, 3)
    W9SLIDE(E_IT, 4)
    #undef E_T
    #undef E_I
    #undef E_TT
    #undef E_II
    #undef E_IT
}

// h-direction 9-sums, sliding quad form. t in [0,80): thread (f,wq,hs)
// produces ho=4hs..4hs+3 for field f, w-quad wq. Reads 12 rows as b128.
__device__ __forceinline__ void hpass(int t, const float* __restrict__ t5,
                                      float* __restrict__ Pbuf)
{
    const int f = t >> 4;
    const int rem = t & 15;
    const int wq = rem >> 2, hs = rem & 3;
    const float* bp = t5 + f * TFS + hs * 4 * TRS + wq * 4;
    float4 r4[12];
    #pragma unroll
    for (int k = 0; k < 12; ++k)
        r4[k] = *reinterpret_cast<const float4*>(bp + k * TRS);
    float sx = r4[0].x, sy = r4[0].y, sz = r4[0].z, sw = r4[0].w;
    #pragma unroll
    for (int k = 1; k < 9; ++k) {
        sx += r4[k].x; sy += r4[k].y; sz += r4[k].z; sw += r4[k].w;
    }
    float* op = Pbuf + f * PFS + hs * 4 * PRS + wq * 4;
    *reinterpret_cast<float4*>(op) = make_float4(sx, sy, sz, sw);
    #pragma unroll
    for (int j = 1; j < 4; ++j) {
        sx += r4[8 + j].x - r4[j - 1].x;
        sy += r4[8 + j].y - r4[j - 1].y;
        sz += r4[8 + j].z - r4[j - 1].z;
        sw += r4[8 + j].w - r4[j - 1].w;
        *reinterpret_cast<float4*>(op + j * PRS) = make_float4(sx, sy, sz, sw);
    }
}

__device__ __forceinline__ float cc_value(const float S[5], float flv)
{
    float wgt = 1.0f / (1.0f + __expf(-flv));   // sigmoid, GAMMA=1
    float Ts = S[0], Is = S[1], TTs = S[2], IIs = S[3], ITs = S[4];
    float Ihat = Is * INV_K;
    float That = Ts * INV_K;
    float cross = ITs - Ihat * Ts - That * Is + That * Ihat * 729.0f;
    float T_var = TTs - 2.0f * That * Ts + That * That * 729.0f;
    float I_var = IIs - 2.0f * Ihat * Is + Ihat * Ihat * 729.0f;
    return cross * cross * wgt / (T_var * I_var + 1e-5f);
}

__global__ void __launch_bounds__(256, 4)
cc3d_main(const float* __restrict__ in, const float* __restrict__ tg,
          const float* __restrict__ fl, double* __restrict__ acc_out)
{
    __shared__ __align__(16) float inT[2][576];
    __shared__ __align__(16) float tgT[2][576];
    __shared__ __align__(16) float tmp5[5 * TFS];
    __shared__ __align__(16) float Pb[2][5 * PFS];
    __shared__ __align__(16) float flT[2][256];
    __shared__ float red[4];
    // LDS: (1152 + 1152 + 2440 + 2640 + 512 + 4)*4 = 31600 B

    const int tid = threadIdx.x;
    const int w0 = blockIdx.x * TW;
    const int h0 = blockIdx.y * TH;
    const int bz = blockIdx.z;
    const int b  = bz / NDCH;
    const int d0 = (bz - b * NDCH) * DCHUNK;
    const int hh = tid >> 4, ww = tid & 15;

    // D-direction ring of 9 plane values per field. At iter l the ring adds
    // plane p = l-1; slot = p % 9 = (li+8) % 9 (compile-time, lb % 9 == 0).
    float ring[45];
    #pragma unroll
    for (int i = 0; i < 45; ++i) ring[i] = 0.f;
    float S[5] = {0.f, 0.f, 0.f, 0.f, 0.f};
    float acc = 0.f;

    // Init halo borders (both buffers): input 0, raw target -1 (-> t = 0).
    {
        float* ifl = &inT[0][0];
        float* tfl = &tgT[0][0];
        for (int i = tid; i < 1152; i += 256) { ifl[i] = 0.f; tfl[i] = -1.f; }
    }
    __syncthreads();
    // Prologue: DMA plane 0 (dp = clamp(d0-4)); garbage filtered by vz.
    dma_plane(in, tg, inT[0], tgT[0], b, max(d0 - 4, 0), h0, w0, tid);

    for (int lb = 0; lb < NIT; lb += 9) {     // lb = 0,9,18,27,36
        #pragma unroll
        for (int li = 0; li < 9; ++li) {
            const int l = lb + li;
            if (l < NIT) {                    // block-uniform
                bar_vm0();   // X: dma(l) -> inT[l&1], flow(l-1) -> flT landed
                // ---- P1: issue dma(l+1), flow(l); step2(l) ----
                {
                    int dpn = d0 + l - 3;                 // plane l+1
                    dpn = min(max(dpn, 0), ND - 1);
                    dma_plane(in, tg, inT[(l + 1) & 1], tgT[(l + 1) & 1],
                              b, dpn, h0, w0, tid);
                }
                {
                    int dout = d0 + l - 8;                // for cc at P2(l+1)
                    dout = min(max(dout, 0), ND - 1);
                    dma_flow(fl, flT[l & 1], b, dout, h0, w0, tid);
                }
                if (tid < 96) step2q(tid, inT[l & 1], tgT[l & 1], tmp5);
                bar_ds();    // W: tmp5 visible; DMAs ride through
                // ---- P2: hpass(l) -> Pb[l&1]; ring plane l-1; cc j=l-9 ----
                if (tid >= 176) hpass(tid - 176, tmp5, Pb[l & 1]);
                if (l >= 1) {
                    const bool vz = ((unsigned)(d0 + l - 5) < (unsigned)ND);
                    const int slot = (li + 8) % 9;        // compile-time
                    const float* pb = Pb[(l - 1) & 1];
                    #pragma unroll
                    for (int f = 0; f < 5; ++f) {
                        float pn = vz ? pb[f * PFS + hh * PRS + ww] : 0.f;
                        S[f] += pn - ring[f * 9 + slot];
                        ring[f * 9 + slot] = pn;
                    }
                    if (l >= 9) {                         // j = l-9 in [0,31]
                        float flv = flT[(l - 1) & 1][tid];
                        acc += cc_value(S, flv);
                    }
                }
            }
        }
    }

    // ---- block reduction -> double atomic into workspace ----
    #pragma unroll
    for (int off = 32; off > 0; off >>= 1) acc += __shfl_down(acc, off);
    if ((tid & 63) == 0) red[tid >> 6] = acc;
    __syncthreads();   // also drains the tail DMAs
    if (tid == 0) {
        double v = (double)red[0] + (double)red[1] + (double)red[2] + (double)red[3];
        atomicAdd(acc_out, v);
    }
}

__global__ void cc3d_finalize(const double* __restrict__ acc, float* __restrict__ out)
{
    out[0] = (float)(-(acc[0] * INV_COUNT));
}

extern "C" void kernel_launch(void* const* d_in, const int* in_sizes, int n_in,
                              void* d_out, int out_size, void* d_ws, size_t ws_size,
                              hipStream_t stream)
{
    const float* in = (const float*)d_in[0];   // 'input'
    const float* tg = (const float*)d_in[1];   // 'target'
    const float* fl = (const float*)d_in[2];   // 'flow'
    float* out = (float*)d_out;
    double* acc = (double*)d_ws;

    hipMemsetAsync(d_ws, 0, sizeof(double), stream);  // graph-safe memset node

    dim3 grid(NW / TW, NH / TH, NB * NDCH);  // (10, 10, 10) = 1000 blocks
    cc3d_main<<<grid, dim3(256), 0, stream>>>(in, tg, fl, acc);
    cc3d_finalize<<<1, 1, 0, stream>>>(acc, out);
}

// Round 10
// 175.182 us; speedup vs baseline: 1.0122x; 1.0122x over previous
//
#include <hip/hip_runtime.h>

// crossCorrelation3D: local (9x9x9) normalized cross-correlation loss, fused.
// B=2, C=1, D=H=W=160, fp32. Output = -mean(cc), scalar.
//
// R10: R9's delayed-drain structure minus R9's bundled overheads.
// R9 post-mortem: regression tracked +7% FETCH (flow-DMA + clamped
// always-issue loads) and sched_barrier(0) pinning — not the drain design.
// R8's residual stall (~400 cyc/iter) = Z-barrier draining a DMA issued in
// the SAME region (near-zero cover). Here the DMA for plane l+1 is issued
// at P1(l) and drained at X(l+1): cover = step2 + W + P2 ~ 600-700 cyc.
//  - Two raw barriers/iter:
//      X = s_waitcnt vmcnt(0) lgkmcnt(0); s_barrier   (iter start)
//      W = s_waitcnt lgkmcnt(0); s_barrier            (DMAs ride through)
//  - iter l: X | P1: dma(l+1)->inT[(l+1)&1] (conditional), flow reg load,
//    step2(l) on inT[l&1] | W | P2: hpass(l)->Pb[l&1], ring(plane l-1 from
//    Pb[(l-1)&1], vz-masked), cc(j=l-9, flv).
//  - Hazards (pairwise): tmp5 w P1(l)/r P2(l): W. r P2(l)/w P1(l+1): X.
//    Pb[l&1] w P2(l)/r ring P2(l+1): X. inT[(l+1)&1] DMA issue P1(l) after
//    X(l) (prior reader step2 P1(l-1) done pre-W(l-1)), lands <= X(l+1),
//    read P1(l+1). flow reg load P1(l) -> use P2(l+1): X between.
//  - d-OOB planes: DMA skipped; buffers hold init zeros (start edge) or
//    stale finite planes (end edge) — both masked by vz at ring (R8-proven).
//  - Borders: exec-masked DMA lanes never write; init inT=0, tgT=-1
//    (transform t=(raw+1)/2 in step2 -> border t=0 = zero-padding).

constexpr int NB = 2;
constexpr int ND = 160;
constexpr int NH = 160;
constexpr int NW = 160;
constexpr int TH = 16;
constexpr int TW = 16;
constexpr int DCHUNK = 32;
constexpr int NDCH = ND / DCHUNK;        // 5
constexpr int NPL = DCHUNK + 8;          // 40 planes
constexpr int NIT = NPL + 1;             // 41 iterations (l = 0..40)
constexpr int TRS = 20;                  // tmp5 row stride (floats)
constexpr int TFS = 24 * TRS + 8;        // 488 (mod 32 = 8: hpass reads even)
constexpr int PRS = 16;                  // Pb row stride
constexpr int PFS = 16 * PRS + 8;        // 264 (mod 32 = 8)
constexpr float INV_K = 1.0f / 729.0f;
constexpr double INV_COUNT = 1.0 / (double(NB) * ND * NH * NW); // 1/8192000

__device__ __forceinline__ void gld_lds16(const float* g, float* l)
{
    __builtin_amdgcn_global_load_lds(
        (const __attribute__((address_space(1))) void*)g,
        (__attribute__((address_space(3))) void*)l, 16, 0, 0);
}

// X barrier: the ONLY vm drain. Waits DMAs issued one full phase + barrier
// + phase earlier (~600-700 cyc cover).
__device__ __forceinline__ void bar_vm0()
{
    asm volatile("s_waitcnt vmcnt(0) lgkmcnt(0)" ::: "memory");
    __builtin_amdgcn_s_barrier();
}
// W barrier: LDS visibility only; in-flight global_load_lds/flow ride through.
__device__ __forceinline__ void bar_ds()
{
    asm volatile("s_waitcnt lgkmcnt(0)" ::: "memory");
    __builtin_amdgcn_s_barrier();
}

// DMA one 24x24 halo plane (input & raw target) into inT/tgT.
// Slot = tid (float4), lane-linear: wave-uniform LDS base + lane*16B.
// OOB (h/w) lanes exec-masked -> border slots keep init (0 / -1) forever.
// dp must be valid [0, ND).
__device__ __forceinline__ void dma_plane(const float* __restrict__ in,
                                          const float* __restrict__ tg,
                                          float* __restrict__ inT,
                                          float* __restrict__ tgT,
                                          int b, int dp, int h0, int w0, int tid)
{
    if (tid < 144) {
        int r = tid / 6;
        int q = tid - r * 6;
        int gh = h0 - 4 + r;
        int gw = w0 - 4 + q * 4;
        int wb = (tid >> 6) * 256;        // wave-uniform float offset
        if (((unsigned)gh < (unsigned)NH) && ((unsigned)gw < (unsigned)NW)) {
            int base = ((b * ND + dp) * NH + gh) * NW + gw;   // fits int32
            gld_lds16(in + base, inT + wb);
            gld_lds16(tg + base, tgT + wb);
        }
    }
}

// w-direction 9-sums, quad form. Thread (r,q): outputs wo=4q..4q+3 of row r
// need inputs 4q..4q+11 (3 b128 per array). Target transform applied HERE
// (tgT holds raw values; border slots = -1 -> t = 0 = zero padding).
#define W9SLIDE(EXPR, FI)                                                  \
    {                                                                      \
        float p0 = (EXPR(0)), p1 = (EXPR(1)), p2 = (EXPR(2)),              \
              p3 = (EXPR(3)), p4 = (EXPR(4)), p5 = (EXPR(5)),              \
              p6 = (EXPR(6)), p7 = (EXPR(7)), p8 = (EXPR(8)),              \
              p9 = (EXPR(9)), p10 = (EXPR(10)), p11 = (EXPR(11));          \
        float s = p0 + p1 + p2 + p3 + p4 + p5 + p6 + p7 + p8;              \
        float4 o;                                                          \
        o.x = s; s += p9 - p0;                                             \
        o.y = s; s += p10 - p1;                                            \
        o.z = s; s += p11 - p2;                                            \
        o.w = s;                                                           \
        *reinterpret_cast<float4*>(outp + (FI) * TFS) = o;                 \
    }

__device__ __forceinline__ void step2q(int tid, const float* __restrict__ inT,
                                       const float* __restrict__ tgT,
                                       float* __restrict__ t5)
{
    const int r = tid >> 2, q = tid & 3;
    const float4* ip = reinterpret_cast<const float4*>(inT + r * 24 + 4 * q);
    const float4* tp = reinterpret_cast<const float4*>(tgT + r * 24 + 4 * q);
    const float4 i0 = ip[0], i1 = ip[1], i2 = ip[2];
    const float4 t0 = tp[0], t1 = tp[1], t2 = tp[2];
    const float ia[12] = {i0.x, i0.y, i0.z, i0.w, i1.x, i1.y, i1.z, i1.w,
                          i2.x, i2.y, i2.z, i2.w};
    float ta[12] = {t0.x, t0.y, t0.z, t0.w, t1.x, t1.y, t1.z, t1.w,
                    t2.x, t2.y, t2.z, t2.w};
    #pragma unroll
    for (int j = 0; j < 12; ++j) ta[j] = fmaf(ta[j], 0.5f, 0.5f);
    float* outp = t5 + r * TRS + 4 * q;
    #define E_T(j)  ta[j]
    #define E_I(j)  ia[j]
    #define E_TT(j) (ta[j] * ta[j])
    #define E_II(j) (ia[j] * ia[j])
    #define E_IT(j) (ia[j] * ta[j])
    W9SLIDE(E_T, 0)
    W9SLIDE(E_I, 1)
    W9SLIDE(E_TT, 2)
    W9SLIDE(E_II, 3)
    W9SLIDE(E_IT, 4)
    #undef E_T
    #undef E_I
    #undef E_TT
    #undef E_II
    #undef E_IT
}

// h-direction 9-sums, sliding quad form. t in [0,80): thread (f,wq,hs)
// produces ho=4hs..4hs+3 for field f, w-quad wq. Reads 12 rows as b128.
__device__ __forceinline__ void hpass(int t, const float* __restrict__ t5,
                                      float* __restrict__ Pbuf)
{
    const int f = t >> 4;
    const int rem = t & 15;
    const int wq = rem >> 2, hs = rem & 3;
    const float* bp = t5 + f * TFS + hs * 4 * TRS + wq * 4;
    float4 r4[12];
    #pragma unroll
    for (int k = 0; k < 12; ++k)
        r4[k] = *reinterpret_cast<const float4*>(bp + k * TRS);
    float sx = r4[0].x, sy = r4[0].y, sz = r4[0].z, sw = r4[0].w;
    #pragma unroll
    for (int k = 1; k < 9; ++k) {
        sx += r4[k].x; sy += r4[k].y; sz += r4[k].z; sw += r4[k].w;
    }
    float* op = Pbuf + f * PFS + hs * 4 * PRS + wq * 4;
    *reinterpret_cast<float4*>(op) = make_float4(sx, sy, sz, sw);
    #pragma unroll
    for (int j = 1; j < 4; ++j) {
        sx += r4[8 + j].x - r4[j - 1].x;
        sy += r4[8 + j].y - r4[j - 1].y;
        sz += r4[8 + j].z - r4[j - 1].z;
        sw += r4[8 + j].w - r4[j - 1].w;
        *reinterpret_cast<float4*>(op + j * PRS) = make_float4(sx, sy, sz, sw);
    }
}

__device__ __forceinline__ float cc_value(const float S[5], float flv)
{
    float wgt = 1.0f / (1.0f + __expf(-flv));   // sigmoid, GAMMA=1
    float Ts = S[0], Is = S[1], TTs = S[2], IIs = S[3], ITs = S[4];
    float Ihat = Is * INV_K;
    float That = Ts * INV_K;
    float cross = ITs - Ihat * Ts - That * Is + That * Ihat * 729.0f;
    float T_var = TTs - 2.0f * That * Ts + That * That * 729.0f;
    float I_var = IIs - 2.0f * Ihat * Is + Ihat * Ihat * 729.0f;
    return cross * cross * wgt / (T_var * I_var + 1e-5f);
}

__global__ void __launch_bounds__(256, 4)
cc3d_main(const float* __restrict__ in, const float* __restrict__ tg,
          const float* __restrict__ fl, double* __restrict__ acc_out)
{
    __shared__ __align__(16) float inT[2][576];
    __shared__ __align__(16) float tgT[2][576];
    __shared__ __align__(16) float tmp5[5 * TFS];
    __shared__ __align__(16) float Pb[2][5 * PFS];
    __shared__ float red[4];
    // LDS: (1152 + 1152 + 2440 + 2640 + 4)*4 = 29552 B

    const int tid = threadIdx.x;
    const int w0 = blockIdx.x * TW;
    const int h0 = blockIdx.y * TH;
    const int bz = blockIdx.z;
    const int b  = bz / NDCH;
    const int d0 = (bz - b * NDCH) * DCHUNK;
    const int hh = tid >> 4, ww = tid & 15;

    // D-direction ring of 9 plane values per field. At iter l the ring adds
    // plane p = l-1; slot = p % 9 = (li+8) % 9 (compile-time, lb % 9 == 0).
    float ring[45];
    #pragma unroll
    for (int i = 0; i < 45; ++i) ring[i] = 0.f;
    float S[5] = {0.f, 0.f, 0.f, 0.f, 0.f};
    float acc = 0.f;
    float flv = 0.f, flv_next = 0.f;

    // Init halo borders (both buffers): input 0, raw target -1 (-> t = 0).
    {
        float* ifl = &inT[0][0];
        float* tfl = &tgT[0][0];
        for (int i = tid; i < 1152; i += 256) { ifl[i] = 0.f; tfl[i] = -1.f; }
    }
    __syncthreads();
    // Prologue: DMA plane 0 (dp = d0-4) into buffer 0 when valid.
    if (d0 - 4 >= 0) dma_plane(in, tg, inT[0], tgT[0], b, d0 - 4, h0, w0, tid);

    for (int lb = 0; lb < NIT; lb += 9) {     // lb = 0,9,18,27,36
        #pragma unroll
        for (int li = 0; li < 9; ++li) {
            const int l = lb + li;
            if (l < NIT) {                    // block-uniform
                bar_vm0();   // X: dma(l) landed in inT[l&1]; Pb[(l-1)&1] visible
                // ---- P1: issue dma(l+1); flow reg load; step2(l) ----
                {
                    const int dpn = d0 + l - 3;           // plane l+1
                    if (l + 1 < NPL && (unsigned)dpn < (unsigned)ND)
                        dma_plane(in, tg, inT[(l + 1) & 1], tgT[(l + 1) & 1],
                                  b, dpn, h0, w0, tid);
                }
                if (l >= 8 && l < 40) {                   // for cc at P2(l+1)
                    const int dout = d0 + l - 8;          // j = l-8 there
                    flv_next = fl[((b * ND + dout) * NH + (h0 + hh)) * NW + (w0 + ww)];
                }
                if (tid < 96) step2q(tid, inT[l & 1], tgT[l & 1], tmp5);
                bar_ds();    // W: tmp5 visible; DMAs/flow ride through
                // ---- P2: hpass(l) -> Pb[l&1]; ring plane l-1; cc j=l-9 ----
                if (tid >= 176) hpass(tid - 176, tmp5, Pb[l & 1]);
                if (l >= 1) {
                    const bool vz = ((unsigned)(d0 + l - 5) < (unsigned)ND);
                    const int slot = (li + 8) % 9;        // compile-time
                    const float* pb = Pb[(l - 1) & 1];
                    #pragma unroll
                    for (int f = 0; f < 5; ++f) {
                        float pn = vz ? pb[f * PFS + hh * PRS + ww] : 0.f;
                        S[f] += pn - ring[f * 9 + slot];
                        ring[f * 9 + slot] = pn;
                    }
                    if (l >= 9) acc += cc_value(S, flv);  // j = l-9 in [0,31]
                }
                flv = flv_next;
            }
        }
    }

    // ---- block reduction -> double atomic into workspace ----
    #pragma unroll
    for (int off = 32; off > 0; off >>= 1) acc += __shfl_down(acc, off);
    if ((tid & 63) == 0) red[tid >> 6] = acc;
    __syncthreads();   // drains any stragglers
    if (tid == 0) {
        double v = (double)red[0] + (double)red[1] + (double)red[2] + (double)red[3];
        atomicAdd(acc_out, v);
    }
}

__global__ void cc3d_finalize(const double* __restrict__ acc, float* __restrict__ out)
{
    out[0] = (float)(-(acc[0] * INV_COUNT));
}

extern "C" void kernel_launch(void* const* d_in, const int* in_sizes, int n_in,
                              void* d_out, int out_size, void* d_ws, size_t ws_size,
                              hipStream_t stream)
{
    const float* in = (const float*)d_in[0];   // 'input'
    const float* tg = (const float*)d_in[1];   // 'target'
    const float* fl = (const float*)d_in[2];   // 'flow'
    float* out = (float*)d_out;
    double* acc = (double*)d_ws;

    hipMemsetAsync(d_ws, 0, sizeof(double), stream);  // graph-safe memset node

    dim3 grid(NW / TW, NH / TH, NB * NDCH);  // (10, 10, 10) = 1000 blocks
    cc3d_main<<<grid, dim3(256), 0, stream>>>(in, tg, fl, acc);
    cc3d_finalize<<<1, 1, 0, stream>>>(acc, out);
}